// Round 4
// baseline (519.387 us; speedup 1.0000x reference)
//
#include <hip/hip_runtime.h>

#define NN 200000
#define DD 128
#define NHH 8
#define HD 16
#define BB 32
#define SS 512
#define QKV_LD 384

#define LDROW16(dst, ptr) do { \
    const float4* _p = (const float4*)(ptr); \
    float4 _a = _p[0], _b = _p[1], _c = _p[2], _d = _p[3]; \
    dst[0]=_a.x; dst[1]=_a.y; dst[2]=_a.z; dst[3]=_a.w; \
    dst[4]=_b.x; dst[5]=_b.y; dst[6]=_b.z; dst[7]=_b.w; \
    dst[8]=_c.x; dst[9]=_c.y; dst[10]=_c.z; dst[11]=_c.w; \
    dst[12]=_d.x; dst[13]=_d.y; dst[14]=_d.z; dst[15]=_d.w; } while(0)

// ---------------------------------------------------------------------------
// K1: tree path-sum + gather. Branchless: all 18 ancestor loads issue
// unconditionally (clamped addr), masked by flag*FMA. One waitcnt drain.
// 8 rows/block, 32 float4-lanes per row.
// ---------------------------------------------------------------------------
__global__ __launch_bounds__(256) void k_gather(const float* __restrict__ feats,
                                                const int* __restrict__ bidx,
                                                float* __restrict__ x) {
    int t = threadIdx.x;
    int r = t >> 5, c4 = t & 31;
    long row = (long)blockIdx.x * 8 + r;
    int idx = bidx[row];
    int v = (idx >= 0 && idx < NN) ? idx : NN;
    const float4* f4 = (const float4*)feats;
    int a[18];
    #pragma unroll
    for (int k = 0; k < 18; ++k) {
        a[k] = v;
        v = (v == 0 || v >= NN) ? NN : (v - 1) >> 1;
    }
    float4 val[18];
    float fl[18];
    #pragma unroll
    for (int k = 0; k < 18; ++k) {
        int aa = a[k] < NN ? a[k] : 0;
        fl[k] = a[k] < NN ? 1.f : 0.f;
        val[k] = f4[(long)aa * 32 + c4];
    }
    float4 acc = make_float4(0.f, 0.f, 0.f, 0.f);
    #pragma unroll
    for (int k = 0; k < 18; ++k) {
        acc.x += fl[k] * val[k].x; acc.y += fl[k] * val[k].y;
        acc.z += fl[k] * val[k].z; acc.w += fl[k] * val[k].w;
    }
    ((float4*)x)[row * 32 + c4] = acc;
}

// ---------------------------------------------------------------------------
// K2: qkv = x @ Win^T + bin. 128x96 tile/block (grid 512 = 2 blocks/CU
// uniform), 8x6 outputs/thread, K staged in 2 chunks of 64, XOR-swizzled LDS.
// ---------------------------------------------------------------------------
__global__ __launch_bounds__(256) void k_qkv(const float* __restrict__ x,
                                             const float* __restrict__ Win,
                                             const float* __restrict__ bin,
                                             float* __restrict__ qkv) {
    __shared__ float4 Xs[128 * 16];   // 32 KB
    __shared__ float4 Ws[96 * 16];    // 24 KB
    int t = threadIdx.x;
    int rb = blockIdx.x >> 2;         // 0..127
    int cb = blockIdx.x & 3;          // 0..3
    long row0 = (long)rb * 128;
    int col0 = cb * 96;
    int ty = t >> 4, tx = t & 15;     // 16x16 grid -> rows ty*8.., cols tx*6..
    float acc[8][6] = {};

    for (int ch = 0; ch < 2; ++ch) {
        const float4* xg = (const float4*)x + row0 * 32 + ch * 16;
        #pragma unroll
        for (int n = 0; n < 8; ++n) {
            int idx = n * 256 + t;            // 0..2047
            int rr = idx >> 4, cc = idx & 15;
            Xs[rr * 16 + (cc ^ (rr & 15))] = xg[(long)rr * 32 + cc];
        }
        const float4* wg = (const float4*)Win + (long)col0 * 32 + ch * 16;
        #pragma unroll
        for (int n = 0; n < 6; ++n) {
            int idx = n * 256 + t;            // 0..1535
            int rr = idx >> 4, cc = idx & 15;
            Ws[rr * 16 + (cc ^ (rr & 15))] = wg[(long)rr * 32 + cc];
        }
        __syncthreads();
        #pragma unroll
        for (int k4 = 0; k4 < 16; ++k4) {
            float4 xa[8], wb[6];
            #pragma unroll
            for (int i = 0; i < 8; ++i) {
                int rr = ty * 8 + i;
                xa[i] = Xs[rr * 16 + (k4 ^ (rr & 15))];
            }
            #pragma unroll
            for (int j = 0; j < 6; ++j) {
                int rr = tx * 6 + j;
                wb[j] = Ws[rr * 16 + (k4 ^ (rr & 15))];
            }
            #pragma unroll
            for (int i = 0; i < 8; ++i)
                #pragma unroll
                for (int j = 0; j < 6; ++j)
                    acc[i][j] += xa[i].x * wb[j].x + xa[i].y * wb[j].y
                               + xa[i].z * wb[j].z + xa[i].w * wb[j].w;
        }
        __syncthreads();
    }
    #pragma unroll
    for (int i = 0; i < 8; ++i) {
        long rr = row0 + ty * 8 + i;
        #pragma unroll
        for (int j = 0; j < 6; ++j) {
            int cc = col0 + tx * 6 + j;
            qkv[rr * QKV_LD + cc] = acc[i][j] + bin[cc];
        }
    }
}

// ---------------------------------------------------------------------------
// K3: flash attention per (b,h). 4 waves; wave w owns keys k == w (mod 4),
// k < len; every wave covers ALL queries (8/thread). K/V read directly from
// global (wave-uniform broadcast, K prefetched, V issued before scores).
// Shifted mask: valid-pair score = dot/4 (no mask ops); pad-key tail and
// all-invalid-query terms in closed form. Defer-max rescale (THR=6).
// 4-way merge via LDS double buffer. Emits t[b,h,:] = sum_q o[q,:].
// ---------------------------------------------------------------------------
__global__ __launch_bounds__(256) void k_attn(const float* __restrict__ qkv,
                                              const int* __restrict__ lengths,
                                              float* __restrict__ tout) {
    __shared__ float mb1[SS][20];   // 40 KB
    __shared__ float mb2[SS][20];   // 40 KB
    int bh = blockIdx.x, b = bh >> 3, h = bh & 7;
    int t = threadIdx.x, lane = t & 63, w = t >> 6;
    int len = lengths[b];
    const float* __restrict__ base = qkv + (long)b * SS * QKV_LD;
    const float* __restrict__ kcol = base + DD + h * HD;
    const float* __restrict__ vcol = base + 2 * DD + h * HD;

    float q[8][HD], acc[8][HD], m[8], l[8];
    #pragma unroll
    for (int j = 0; j < 8; ++j) {
        int qi = lane + 64 * j;   // pad q-rows are exactly zero, load freely
        const float4* qp = (const float4*)(base + (long)qi * QKV_LD + h * HD);
        #pragma unroll
        for (int c = 0; c < 4; ++c) {
            float4 qv = qp[c];
            q[j][c*4+0] = qv.x * 0.25f; q[j][c*4+1] = qv.y * 0.25f;
            q[j][c*4+2] = qv.z * 0.25f; q[j][c*4+3] = qv.w * 0.25f;
        }
        m[j] = -1e30f; l[j] = 0.f;
        #pragma unroll
        for (int d = 0; d < HD; ++d) acc[j][d] = 0.f;
    }

    int cnt = (len - w + 3) >> 2;   // keys w+4i, i<cnt (len>=256 -> cnt>=64)
    int G = (cnt + 1) >> 1;         // 2-key groups

    float kf[2][HD], vf[2][HD];
    {
        int k0 = w, k1 = w + 4;
        LDROW16(kf[0], kcol + (long)(k0 < SS ? k0 : SS - 1) * QKV_LD);
        LDROW16(kf[1], kcol + (long)(k1 < SS ? k1 : SS - 1) * QKV_LD);
    }
    for (int g = 0; g < G; ++g) {
        int k0 = w + 8 * g, k1 = k0 + 4;
        bool kv0 = k0 < len, kv1 = k1 < len;
        // V issued early; consumed after scores phase (latency hidden)
        LDROW16(vf[0], vcol + (long)(k0 < SS ? k0 : SS - 1) * QKV_LD);
        LDROW16(vf[1], vcol + (long)(k1 < SS ? k1 : SS - 1) * QKV_LD);
        float s0[8], s1[8];
        #pragma unroll
        for (int j = 0; j < 8; ++j) {
            if (64 * j < len || j == 7) {
                float a0 = 0.f, a1 = 0.f;
                #pragma unroll
                for (int d = 0; d < HD; ++d) {
                    a0 += q[j][d] * kf[0][d];
                    a1 += q[j][d] * kf[1][d];
                }
                s0[j] = kv0 ? a0 : -1e30f;
                s1[j] = kv1 ? a1 : -1e30f;
            }
        }
        // prefetch next K group (consumed next iteration)
        if (g + 1 < G) {
            int n0 = w + 8 * g + 8, n1 = n0 + 4;
            LDROW16(kf[0], kcol + (long)(n0 < SS ? n0 : SS - 1) * QKV_LD);
            LDROW16(kf[1], kcol + (long)(n1 < SS ? n1 : SS - 1) * QKV_LD);
        }
        #pragma unroll
        for (int j = 0; j < 8; ++j) {
            if (64 * j < len || j == 7) {
                float gm = fmaxf(s0[j], s1[j]);
                if (gm > m[j] + 6.f) {   // defer-max: usually all-lanes-skip
                    float sc = __expf(m[j] - gm);
                    m[j] = gm; l[j] *= sc;
                    #pragma unroll
                    for (int d = 0; d < HD; ++d) acc[j][d] *= sc;
                }
                float p0 = __expf(s0[j] - m[j]);
                float p1 = __expf(s1[j] - m[j]);
                l[j] += p0 + p1;
                #pragma unroll
                for (int d = 0; d < HD; ++d)
                    acc[j][d] += p0 * vf[0][d] + p1 * vf[1][d];
            }
        }
    }

    // ---- merge 4 wave-partials: (w1,w3) write; (w0,w2) merge; w2 writes; w0 final
    if (w == 1 || w == 3) {
        float (*mb)[20] = (w == 1) ? mb1 : mb2;
        #pragma unroll
        for (int j = 0; j < 8; ++j) if (64 * j < len || j == 7) {
            int qi = lane + 64 * j;
            mb[qi][0] = m[j]; mb[qi][1] = l[j];
            #pragma unroll
            for (int d = 0; d < HD; ++d) mb[qi][4 + d] = acc[j][d];
        }
    }
    __syncthreads();
    if (w == 0 || w == 2) {
        float (*mb)[20] = (w == 0) ? mb1 : mb2;
        #pragma unroll
        for (int j = 0; j < 8; ++j) if (64 * j < len || j == 7) {
            int qi = lane + 64 * j;
            float m2 = mb[qi][0], l2 = mb[qi][1];
            float M = fmaxf(m[j], m2);
            float wa = __expf(m[j] - M), wb = __expf(m2 - M);
            l[j] = l[j] * wa + l2 * wb;
            m[j] = M;
            #pragma unroll
            for (int d = 0; d < HD; ++d)
                acc[j][d] = acc[j][d] * wa + mb[qi][4 + d] * wb;
        }
    }
    __syncthreads();
    if (w == 2) {
        #pragma unroll
        for (int j = 0; j < 8; ++j) if (64 * j < len || j == 7) {
            int qi = lane + 64 * j;
            mb1[qi][0] = m[j]; mb1[qi][1] = l[j];
            #pragma unroll
            for (int d = 0; d < HD; ++d) mb1[qi][4 + d] = acc[j][d];
        }
    }
    __syncthreads();
    if (w == 0) {
        #pragma unroll
        for (int j = 0; j < 8; ++j) if (64 * j < len || j == 7) {
            int qi = lane + 64 * j;
            float m2 = mb1[qi][0], l2 = mb1[qi][1];
            float M = fmaxf(m[j], m2);
            float wa = __expf(m[j] - M), wb = __expf(m2 - M);
            l[j] = l[j] * wa + l2 * wb;
            m[j] = M;
            #pragma unroll
            for (int d = 0; d < HD; ++d)
                acc[j][d] = acc[j][d] * wa + mb1[qi][4 + d] * wb;
        }
        float osum[HD];
        #pragma unroll
        for (int d = 0; d < HD; ++d) osum[d] = 0.f;
        #pragma unroll
        for (int j = 0; j < 8; ++j) if (64 * j < len || j == 7) {
            int qi = lane + 64 * j;
            if (qi < len) {   // valid query: add pad-key tail, normalize
                float tl = l[j] + (float)(SS - len) * __expf(-1.f - m[j]);
                float inv = 1.f / tl;
                #pragma unroll
                for (int d = 0; d < HD; ++d) osum[d] += acc[j][d] * inv;
            }
        }
        // all invalid queries collapse to (512-len)/512 * sum_valid(v):
        // lane63/j7 slot (q==0) accumulated exactly sum_valid(v) in acc[7]
        if (lane == 63 && len < SS) {
            float sc = (float)(SS - len) / (float)SS;
            #pragma unroll
            for (int d = 0; d < HD; ++d) osum[d] += acc[7][d] * sc;
        }
        #pragma unroll
        for (int d = 0; d < HD; ++d) {
            float v = osum[d];
            for (int off = 32; off >= 1; off >>= 1) v += __shfl_down(v, off, 64);
            osum[d] = v;
        }
        if (lane == 0) {
            float* o = tout + bh * HD;
            #pragma unroll
            for (int d = 0; d < HD; ++d) o[d] = osum[d];
        }
    }
}

// ---------------------------------------------------------------------------
// K4: out[b,d] = sum_c t[b,c] * Wout[d,c] + S * bout[d]
// ---------------------------------------------------------------------------
__global__ __launch_bounds__(DD) void k_out(const float* __restrict__ tsum,
                                            const float* __restrict__ Wout,
                                            const float* __restrict__ bout,
                                            float* __restrict__ out) {
    int b = blockIdx.x;
    int d = threadIdx.x;
    __shared__ float tr[DD];
    tr[d] = tsum[b * DD + d];
    __syncthreads();
    float s = (float)SS * bout[d];
    #pragma unroll 8
    for (int c = 0; c < DD; ++c) s += tr[c] * Wout[d * DD + c];
    out[b * DD + d] = s;
}

extern "C" void kernel_launch(void* const* d_in, const int* in_sizes, int n_in,
                              void* d_out, int out_size, void* d_ws, size_t ws_size,
                              hipStream_t stream) {
    const float* feats = (const float*)d_in[0];
    const float* Win   = (const float*)d_in[1];
    const float* bin   = (const float*)d_in[2];
    const float* Wout  = (const float*)d_in[3];
    const float* bout  = (const float*)d_in[4];
    const int* bidx    = (const int*)d_in[7];
    const int* lengths = (const int*)d_in[8];
    float* out = (float*)d_out;

    char* ws = (char*)d_ws;
    float* x    = (float*)ws;                       // 8 MB
    float* qkv  = (float*)(ws + 8388608);           // 24 MB
    float* tsum = (float*)(ws + 8388608 + 25165824);

    k_gather<<<BB * SS / 8, 256, 0, stream>>>(feats, bidx, x);
    k_qkv<<<512, 256, 0, stream>>>(x, Win, bin, qkv);
    k_attn<<<BB * NHH, 256, 0, stream>>>(qkv, lengths, tsum);
    k_out<<<BB, DD, 0, stream>>>(tsum, Wout, bout, out);
}

// Round 5
// 290.887 us; speedup vs baseline: 1.7855x; 1.7855x over previous
//
#include <hip/hip_runtime.h>

#define NN 200000
#define DD 128
#define NHH 8
#define HD 16
#define BB 32
#define SS 512
#define QKV_LD 384

typedef __attribute__((ext_vector_type(8))) short short8;
typedef __attribute__((ext_vector_type(4))) float f32x4;

static __device__ __forceinline__ unsigned short f2bf(float f) {
    unsigned u = __float_as_uint(f);
    unsigned r = (u + 0x7FFFu + ((u >> 16) & 1u)) >> 16;   // RNE
    return (unsigned short)r;
}

#define LDROW16S(dst, ptr, sc) do { \
    const float4* _p = (const float4*)(ptr); \
    float4 _a = _p[0], _b = _p[1], _c = _p[2], _d = _p[3]; \
    dst[0]=_a.x*sc; dst[1]=_a.y*sc; dst[2]=_a.z*sc; dst[3]=_a.w*sc; \
    dst[4]=_b.x*sc; dst[5]=_b.y*sc; dst[6]=_b.z*sc; dst[7]=_b.w*sc; \
    dst[8]=_c.x*sc; dst[9]=_c.y*sc; dst[10]=_c.z*sc; dst[11]=_c.w*sc; \
    dst[12]=_d.x*sc; dst[13]=_d.y*sc; dst[14]=_d.z*sc; dst[15]=_d.w*sc; } while(0)

// ---------------------------------------------------------------------------
// K1: tree path-sum + gather. Branchless 18 ancestor loads (clamped addr,
// flag*FMA mask), one drain. Output in bf16 (feeds MFMA qkv).
// ---------------------------------------------------------------------------
__global__ __launch_bounds__(256) void k_gather(const float* __restrict__ feats,
                                                const int* __restrict__ bidx,
                                                unsigned short* __restrict__ xb) {
    int t = threadIdx.x;
    int r = t >> 5, c4 = t & 31;
    long row = (long)blockIdx.x * 8 + r;
    int idx = bidx[row];
    int v = (idx >= 0 && idx < NN) ? idx : NN;
    const float4* f4 = (const float4*)feats;
    int a[18];
    #pragma unroll
    for (int k = 0; k < 18; ++k) {
        a[k] = v;
        v = (v == 0 || v >= NN) ? NN : (v - 1) >> 1;
    }
    float4 val[18];
    float fl[18];
    #pragma unroll
    for (int k = 0; k < 18; ++k) {
        int aa = a[k] < NN ? a[k] : 0;
        fl[k] = a[k] < NN ? 1.f : 0.f;
        val[k] = f4[(long)aa * 32 + c4];
    }
    float4 acc = make_float4(0.f, 0.f, 0.f, 0.f);
    #pragma unroll
    for (int k = 0; k < 18; ++k) {
        acc.x += fl[k] * val[k].x; acc.y += fl[k] * val[k].y;
        acc.z += fl[k] * val[k].z; acc.w += fl[k] * val[k].w;
    }
    ushort4 o;
    o.x = f2bf(acc.x); o.y = f2bf(acc.y); o.z = f2bf(acc.z); o.w = f2bf(acc.w);
    ((ushort4*)xb)[row * 32 + c4] = o;
}

// ---------------------------------------------------------------------------
// K1b: Win fp32 -> bf16 (49152 elements).
// ---------------------------------------------------------------------------
__global__ __launch_bounds__(256) void k_wconv(const float* __restrict__ W,
                                               unsigned short* __restrict__ Wb) {
    int i = (blockIdx.x * 256 + threadIdx.x) * 4;
    float4 v = *(const float4*)(W + i);
    ushort4 o;
    o.x = f2bf(v.x); o.y = f2bf(v.y); o.z = f2bf(v.z); o.w = f2bf(v.w);
    *(ushort4*)(Wb + i) = o;
}

// ---------------------------------------------------------------------------
// K2: qkv = x @ Win^T + bin via bf16 MFMA (gemm_bt pattern, verified layout).
// Block = 128x128 tile (grid 128x3), 4 waves = 2x2 quadrants of 64x64.
// LDS: A,B tiles 128x128 bf16 as 16B chunks, XOR swizzle c^(r&15).
// K=128 -> 4 MFMA K-steps, no K-loop staging. Output fp32 + bias.
// ---------------------------------------------------------------------------
__global__ __launch_bounds__(256) void k_qkv(const unsigned short* __restrict__ xb,
                                             const unsigned short* __restrict__ Wb,
                                             const float* __restrict__ bin,
                                             float* __restrict__ qkv) {
    __shared__ uint4 As4[128 * 16];   // 32 KB
    __shared__ uint4 Bs4[128 * 16];   // 32 KB
    int t = threadIdx.x;
    int rb = blockIdx.x / 3, cb = blockIdx.x % 3;
    long row0 = (long)rb * 128;
    int col0 = cb * 128;
    const uint4* ag = (const uint4*)xb + row0 * 16;
    const uint4* bg = (const uint4*)Wb + (long)col0 * 16;
    #pragma unroll
    for (int n = 0; n < 8; ++n) {
        int idx = n * 256 + t;            // 0..2047
        int r = idx >> 4, c = idx & 15;
        int p = r * 16 + (c ^ (r & 15));
        As4[p] = ag[idx];
        Bs4[p] = bg[idx];
    }
    __syncthreads();

    int lane = t & 63, w = t >> 6;
    int wr = (w >> 1) * 64, wc = (w & 1) * 64;
    int frow = lane & 15, fk = lane >> 4;
    f32x4 acc[4][4] = {};
    const short8* A8 = (const short8*)As4;
    const short8* B8 = (const short8*)Bs4;
    #pragma unroll
    for (int ks = 0; ks < 4; ++ks) {
        int chunk = ks * 4 + fk;
        short8 af[4], bf[4];
        #pragma unroll
        for (int mi = 0; mi < 4; ++mi) {
            int r = wr + mi * 16 + frow;
            af[mi] = A8[r * 16 + (chunk ^ (r & 15))];
        }
        #pragma unroll
        for (int ni = 0; ni < 4; ++ni) {
            int r = wc + ni * 16 + frow;
            bf[ni] = B8[r * 16 + (chunk ^ (r & 15))];
        }
        #pragma unroll
        for (int mi = 0; mi < 4; ++mi)
            #pragma unroll
            for (int ni = 0; ni < 4; ++ni)
                acc[mi][ni] = __builtin_amdgcn_mfma_f32_16x16x32_bf16(
                    af[mi], bf[ni], acc[mi][ni], 0, 0, 0);
    }

    int rg = lane >> 4;   // C/D: col = lane&15, row = rg*4 + j
    #pragma unroll
    for (int ni = 0; ni < 4; ++ni) {
        int col = col0 + wc + ni * 16 + frow;
        float bb = bin[col];
        #pragma unroll
        for (int mi = 0; mi < 4; ++mi) {
            #pragma unroll
            for (int j = 0; j < 4; ++j) {
                long r = row0 + wr + mi * 16 + rg * 4 + j;
                qkv[r * QKV_LD + col] = acc[mi][ni][j] + bb;
            }
        }
    }
}

// ---------------------------------------------------------------------------
// K3: flash attention, 1 query/thread. Block = (b,h,qhalf): 256 queries.
// K/V read from global at wave-uniform addresses (scalar/broadcast loads,
// no LDS, tiny VGPR). Shifted mask (valid score = dot/4), closed-form
// pad-key tail, invalid queries unify via m=0,p=1. Defer-max THR=6.
// Writes per-block query-summed partial [512][16].
// ---------------------------------------------------------------------------
__global__ __launch_bounds__(256) void k_attn(const float* __restrict__ qkv,
                                              const int* __restrict__ lengths,
                                              float* __restrict__ tpart) {
    int blk = blockIdx.x;
    int bh = blk >> 1, half = blk & 1;
    int b = bh >> 3, h = bh & 7;
    int t = threadIdx.x;
    int qi = half * 256 + t;
    int len = lengths[b];
    const float* __restrict__ base = qkv + (long)b * SS * QKV_LD;
    const float* __restrict__ kcol = base + DD + h * HD;
    const float* __restrict__ vcol = base + 2 * DD + h * HD;

    float q[HD];
    LDROW16S(q, base + (long)qi * QKV_LD + h * HD, 0.25f);

    float m = -1e30f, l = 0.f;
    float acc[HD];
    #pragma unroll
    for (int d = 0; d < HD; ++d) acc[d] = 0.f;

    int G = (len + 1) >> 1;           // 2-key groups over valid keys
    float kf[2][HD], vf[2][HD];
    LDROW16S(kf[0], kcol + 0 * QKV_LD, 1.f);
    LDROW16S(kf[1], kcol + 1 * QKV_LD, 1.f);

    for (int g = 0; g < G; ++g) {
        int k0 = 2 * g, k1 = 2 * g + 1;
        // V for current group issued early (hidden under score compute)
        LDROW16S(vf[0], vcol + (long)k0 * QKV_LD, 1.f);
        LDROW16S(vf[1], vcol + (long)k1 * QKV_LD, 1.f);
        float s0 = 0.f, s1 = 0.f;
        #pragma unroll
        for (int d = 0; d < HD; ++d) {
            s0 += q[d] * kf[0][d];
            s1 += q[d] * kf[1][d];
        }
        if (k1 >= len) s1 = -1e30f;   // odd-len tail
        // prefetch next K group (clamped, unconditional)
        int n0 = 2 * g + 2; n0 = n0 < SS ? n0 : SS - 1;
        int n1 = 2 * g + 3; n1 = n1 < SS ? n1 : SS - 1;
        LDROW16S(kf[0], kcol + (long)n0 * QKV_LD, 1.f);
        LDROW16S(kf[1], kcol + (long)n1 * QKV_LD, 1.f);

        float gm = fmaxf(s0, s1);
        if (gm > m + 6.f) {           // defer-max rescale
            float sc = __expf(m - gm);
            m = gm; l *= sc;
            #pragma unroll
            for (int d = 0; d < HD; ++d) acc[d] *= sc;
        }
        float p0 = __expf(s0 - m);
        float p1 = __expf(s1 - m);
        l += p0 + p1;
        #pragma unroll
        for (int d = 0; d < HD; ++d)
            acc[d] += p0 * vf[0][d] + p1 * vf[1][d];
    }

    float contrib[HD];
    if (qi < len) {
        float tl = l + (float)(SS - len) * __expf(-1.f - m);
        float inv = 1.f / tl;
        #pragma unroll
        for (int d = 0; d < HD; ++d) contrib[d] = acc[d] * inv;
    } else {
        // invalid query: softmax uniform over 512 keys -> acc(=sum_valid v)/512
        #pragma unroll
        for (int d = 0; d < HD; ++d) contrib[d] = acc[d] * (1.f / (float)SS);
    }

    __shared__ float red[4][HD];
    int lane = t & 63, wv = t >> 6;
    #pragma unroll
    for (int d = 0; d < HD; ++d) {
        float v = contrib[d];
        for (int off = 32; off >= 1; off >>= 1) v += __shfl_down(v, off, 64);
        if (lane == 0) red[wv][d] = v;
    }
    __syncthreads();
    if (t < HD) {
        tpart[blk * HD + t] = red[0][t] + red[1][t] + red[2][t] + red[3][t];
    }
}

// ---------------------------------------------------------------------------
// K4: out[b,d] = sum_c t[b,c]*Wout[d,c] + S*bout[d]; t from 2 half-partials.
// ---------------------------------------------------------------------------
__global__ __launch_bounds__(DD) void k_out(const float* __restrict__ tpart,
                                            const float* __restrict__ Wout,
                                            const float* __restrict__ bout,
                                            float* __restrict__ out) {
    int b = blockIdx.x;
    int d = threadIdx.x;
    __shared__ float tr[DD];
    int bh = b * 8 + (d >> 4), dd = d & 15;
    tr[d] = tpart[(bh * 2 + 0) * HD + dd] + tpart[(bh * 2 + 1) * HD + dd];
    __syncthreads();
    float s = (float)SS * bout[d];
    #pragma unroll 8
    for (int c = 0; c < DD; ++c) s += tr[c] * Wout[d * DD + c];
    out[b * DD + d] = s;
}

extern "C" void kernel_launch(void* const* d_in, const int* in_sizes, int n_in,
                              void* d_out, int out_size, void* d_ws, size_t ws_size,
                              hipStream_t stream) {
    const float* feats = (const float*)d_in[0];
    const float* Win   = (const float*)d_in[1];
    const float* bin   = (const float*)d_in[2];
    const float* Wout  = (const float*)d_in[3];
    const float* bout  = (const float*)d_in[4];
    const int* bidx    = (const int*)d_in[7];
    const int* lengths = (const int*)d_in[8];
    float* out = (float*)d_out;

    char* ws = (char*)d_ws;
    unsigned short* xb = (unsigned short*)ws;                 // 4 MB bf16
    unsigned short* Wb = (unsigned short*)(ws + 4194304);     // 96 KB bf16
    float* qkv  = (float*)(ws + 8388608);                     // 24 MB fp32
    float* tpart = (float*)(ws + 8388608 + 25165824);         // 32 KB

    k_gather<<<BB * SS / 8, 256, 0, stream>>>(feats, bidx, xb);
    k_wconv<<<48, 256, 0, stream>>>(Win, Wb);
    k_qkv<<<128 * 3, 256, 0, stream>>>(xb, Wb, bin, qkv);
    k_attn<<<BB * NHH * 2, 256, 0, stream>>>(qkv, lengths, tpart);
    k_out<<<BB, DD, 0, stream>>>(tpart, Wout, bout, out);
}

// Round 6
// 268.928 us; speedup vs baseline: 1.9313x; 1.0817x over previous
//
#include <hip/hip_runtime.h>

#define NN 200000
#define DD 128
#define NHH 8
#define HD 16
#define BB 32
#define SS 512
#define QKV_LD 384

typedef __attribute__((ext_vector_type(8))) short short8;
typedef __attribute__((ext_vector_type(4))) float f32x4;

static __device__ __forceinline__ unsigned short f2bf(float f) {
    unsigned u = __float_as_uint(f);
    unsigned r = (u + 0x7FFFu + ((u >> 16) & 1u)) >> 16;   // RNE
    return (unsigned short)r;
}
static __device__ __forceinline__ unsigned pk2(float a, float b) {
    return (unsigned)f2bf(a) | ((unsigned)f2bf(b) << 16);
}
static __device__ __forceinline__ unsigned cvtpk(float a, float b) {
    unsigned r;
    asm("v_cvt_pk_bf16_f32 %0, %1, %2" : "=v"(r) : "v"(a), "v"(b));
    return r;
}

// ---------------------------------------------------------------------------
// K1: tree path-sum + gather -> bf16. Branchless 18 ancestor loads.
// ---------------------------------------------------------------------------
__global__ __launch_bounds__(256) void k_gather(const float* __restrict__ feats,
                                                const int* __restrict__ bidx,
                                                unsigned short* __restrict__ xb) {
    int t = threadIdx.x;
    int r = t >> 5, c4 = t & 31;
    long row = (long)blockIdx.x * 8 + r;
    int idx = bidx[row];
    int v = (idx >= 0 && idx < NN) ? idx : NN;
    const float4* f4 = (const float4*)feats;
    int a[18];
    #pragma unroll
    for (int k = 0; k < 18; ++k) {
        a[k] = v;
        v = (v == 0 || v >= NN) ? NN : (v - 1) >> 1;
    }
    float4 val[18];
    float fl[18];
    #pragma unroll
    for (int k = 0; k < 18; ++k) {
        int aa = a[k] < NN ? a[k] : 0;
        fl[k] = a[k] < NN ? 1.f : 0.f;
        val[k] = f4[(long)aa * 32 + c4];
    }
    float4 acc = make_float4(0.f, 0.f, 0.f, 0.f);
    #pragma unroll
    for (int k = 0; k < 18; ++k) {
        acc.x += fl[k] * val[k].x; acc.y += fl[k] * val[k].y;
        acc.z += fl[k] * val[k].z; acc.w += fl[k] * val[k].w;
    }
    ushort4 o;
    o.x = f2bf(acc.x); o.y = f2bf(acc.y); o.z = f2bf(acc.z); o.w = f2bf(acc.w);
    ((ushort4*)xb)[row * 32 + c4] = o;
}

// ---------------------------------------------------------------------------
// K1b: Win fp32 -> bf16.
// ---------------------------------------------------------------------------
__global__ __launch_bounds__(256) void k_wconv(const float* __restrict__ W,
                                               unsigned short* __restrict__ Wb) {
    int i = (blockIdx.x * 256 + threadIdx.x) * 4;
    float4 v = *(const float4*)(W + i);
    ushort4 o;
    o.x = f2bf(v.x); o.y = f2bf(v.y); o.z = f2bf(v.z); o.w = f2bf(v.w);
    *(ushort4*)(Wb + i) = o;
}

// ---------------------------------------------------------------------------
// K2: qkv = x @ Win^T + bin via bf16 MFMA (verified layout; unchanged).
// ---------------------------------------------------------------------------
__global__ __launch_bounds__(256) void k_qkv(const unsigned short* __restrict__ xb,
                                             const unsigned short* __restrict__ Wb,
                                             const float* __restrict__ bin,
                                             float* __restrict__ qkv) {
    __shared__ uint4 As4[128 * 16];
    __shared__ uint4 Bs4[128 * 16];
    int t = threadIdx.x;
    int rb = blockIdx.x / 3, cb = blockIdx.x % 3;
    long row0 = (long)rb * 128;
    int col0 = cb * 128;
    const uint4* ag = (const uint4*)xb + row0 * 16;
    const uint4* bg = (const uint4*)Wb + (long)col0 * 16;
    #pragma unroll
    for (int n = 0; n < 8; ++n) {
        int idx = n * 256 + t;
        int r = idx >> 4, c = idx & 15;
        int p = r * 16 + (c ^ (r & 15));
        As4[p] = ag[idx];
        Bs4[p] = bg[idx];
    }
    __syncthreads();

    int lane = t & 63, w = t >> 6;
    int wr = (w >> 1) * 64, wc = (w & 1) * 64;
    int frow = lane & 15, fk = lane >> 4;
    f32x4 acc[4][4] = {};
    const short8* A8 = (const short8*)As4;
    const short8* B8 = (const short8*)Bs4;
    #pragma unroll
    for (int ks = 0; ks < 4; ++ks) {
        int chunk = ks * 4 + fk;
        short8 af[4], bf[4];
        #pragma unroll
        for (int mi = 0; mi < 4; ++mi) {
            int r = wr + mi * 16 + frow;
            af[mi] = A8[r * 16 + (chunk ^ (r & 15))];
        }
        #pragma unroll
        for (int ni = 0; ni < 4; ++ni) {
            int r = wc + ni * 16 + frow;
            bf[ni] = B8[r * 16 + (chunk ^ (r & 15))];
        }
        #pragma unroll
        for (int mi = 0; mi < 4; ++mi)
            #pragma unroll
            for (int ni = 0; ni < 4; ++ni)
                acc[mi][ni] = __builtin_amdgcn_mfma_f32_16x16x32_bf16(
                    af[mi], bf[ni], acc[mi][ni], 0, 0, 0);
    }

    int rg = lane >> 4;
    #pragma unroll
    for (int ni = 0; ni < 4; ++ni) {
        int col = col0 + wc + ni * 16 + frow;
        float bb = bin[col];
        #pragma unroll
        for (int mi = 0; mi < 4; ++mi) {
            #pragma unroll
            for (int j = 0; j < 4; ++j) {
                long r = row0 + wr + mi * 16 + rg * 4 + j;
                qkv[r * QKV_LD + col] = acc[mi][ni][j] + bb;
            }
        }
    }
}

// ---------------------------------------------------------------------------
// K2b: repack qkv fp32 -> MFMA frag layouts (bf16) + Vsum.
// Qf/Kf: per (bh, tile of 16 tokens), 32 lanes x 16B: lane<32 holds
//   token=tile*16+(lane&15), d = (lane>>4)*8..+7 (upper half of padded K=32
//   is implicit zeros, not stored). Q pre-scaled by 0.25.
// Vf: per (bh, super of 32 tokens), 64 lanes x 16B: d=lane&15,
//   tokens = super*32+(lane>>4)*8..+7 (V^T frags, A-operand of O^T=V^T P^T).
// Vsum[bh][d] = sum over all 512 tokens of V (pad rows are exactly 0).
// ---------------------------------------------------------------------------
__global__ __launch_bounds__(256) void k_repack(const float* __restrict__ qkv,
                                                uint4* __restrict__ Qf,
                                                uint4* __restrict__ Kf,
                                                uint4* __restrict__ Vf,
                                                float* __restrict__ Vsum) {
    int bh = blockIdx.x, b = bh >> 3, h = bh & 7;
    int t = threadIdx.x;
    const float* base = qkv + (long)b * SS * QKV_LD;

    // Q/K frags: lanes = t&31, 8 tiles per pass, 4 passes
    int l32 = t & 31, sub = t >> 5;
    int r16 = l32 & 15, g2 = l32 >> 4;          // g2 in {0,1}
    #pragma unroll
    for (int pass = 0; pass < 4; ++pass) {
        int qt = pass * 8 + sub;
        const float* qp = base + (long)(qt * 16 + r16) * QKV_LD + h * HD + 8 * g2;
        float4 f0 = *(const float4*)qp;
        float4 f1 = *(const float4*)(qp + 4);
        uint4 uq;
        uq.x = pk2(f0.x * 0.25f, f0.y * 0.25f);
        uq.y = pk2(f0.z * 0.25f, f0.w * 0.25f);
        uq.z = pk2(f1.x * 0.25f, f1.y * 0.25f);
        uq.w = pk2(f1.z * 0.25f, f1.w * 0.25f);
        Qf[((long)bh * 32 + qt) * 32 + l32] = uq;
        const float* kp = qp + DD;
        float4 k0 = *(const float4*)kp;
        float4 k1 = *(const float4*)(kp + 4);
        uint4 uk;
        uk.x = pk2(k0.x, k0.y); uk.y = pk2(k0.z, k0.w);
        uk.z = pk2(k1.x, k1.y); uk.w = pk2(k1.z, k1.w);
        Kf[((long)bh * 32 + qt) * 32 + l32] = uk;
    }

    // V frags + Vsum: lanes = t&63, 4 supers per pass, 4 passes
    int lane = t & 63, vsub = t >> 6;
    int d = lane & 15, gg = lane >> 4;
    float vpart = 0.f;
    #pragma unroll
    for (int pass = 0; pass < 4; ++pass) {
        int kts = pass * 4 + vsub;
        int k0 = kts * 32 + gg * 8;
        float vv[8];
        #pragma unroll
        for (int i = 0; i < 8; ++i)
            vv[i] = base[(long)(k0 + i) * QKV_LD + 2 * DD + h * HD + d];
        #pragma unroll
        for (int i = 0; i < 8; ++i) vpart += vv[i];
        uint4 uv;
        uv.x = pk2(vv[0], vv[1]); uv.y = pk2(vv[2], vv[3]);
        uv.z = pk2(vv[4], vv[5]); uv.w = pk2(vv[6], vv[7]);
        Vf[((long)bh * 16 + kts) * 64 + lane] = uv;
    }
    __shared__ float vred[256];
    vred[t] = vpart;
    __syncthreads();
    if (t < HD) {
        float s = 0.f;
        #pragma unroll
        for (int j = 0; j < 16; ++j) s += vred[t + j * 16];
        Vsum[bh * HD + t] = s;
    }
}

// ---------------------------------------------------------------------------
// K3: MFMA flash attention. Block = (bh, qhalf), 4 waves, each wave 4
// q-tiles of 16 queries. S^T = K Q^T (padded K=32) -> per-lane softmax
// (in-lane + 2 shuffles) -> pack P to bf16 -> LDS bounce into B-frag layout
// -> O^T = V^T P^T accumulated over 32-token super-tiles.
// Shifted mask: valid score = dot/4 (0.25 folded into Q); pad keys = -1
// handled via m init and closed-form tail; invalid queries dropped here
// (closed-form in k_out). Writes tpart[blk][16] = sum_q o[q][:].
// ---------------------------------------------------------------------------
__global__ __launch_bounds__(256) void k_attn(const uint4* __restrict__ Qf,
                                              const uint4* __restrict__ Kf,
                                              const uint4* __restrict__ Vf,
                                              const int* __restrict__ lengths,
                                              float* __restrict__ tpart) {
    int blk = blockIdx.x;
    int bh = blk >> 1, half = blk & 1;
    int b = bh >> 3;
    int t = threadIdx.x, lane = t & 63, w = t >> 6;
    int len = lengths[b];
    int q15 = lane & 15, g = lane >> 4;
    int nsup = (len + 31) >> 5;       // super-tiles with any valid token
    int ntk = nsup * 2;               // 16-token S tiles to compute

    __shared__ unsigned pbuf[4][256];
    __shared__ float red[4][HD];
    unsigned* pw = &pbuf[w][0];

    float osum[4] = {0.f, 0.f, 0.f, 0.f};
    const uint4 z4 = make_uint4(0u, 0u, 0u, 0u);

    #pragma unroll
    for (int i = 0; i < 4; ++i) {
        int qt = half * 16 + w * 4 + i;
        if (qt * 16 >= len) continue;            // fully-invalid q-tile

        uint4 qfu = (lane < 32) ? Qf[((long)bh * 32 + qt) * 32 + lane] : z4;
        short8 qf = __builtin_bit_cast(short8, qfu);

        f32x4 sacc[32];
        #pragma unroll
        for (int kt = 0; kt < 32; ++kt) {
            if (kt < ntk) {
                uint4 kfu = (lane < 32) ? Kf[((long)bh * 32 + kt) * 32 + lane] : z4;
                f32x4 cz = {0.f, 0.f, 0.f, 0.f};
                sacc[kt] = __builtin_amdgcn_mfma_f32_16x16x32_bf16(
                    __builtin_bit_cast(short8, kfu), qf, cz, 0, 0, 0);
            }
        }
        // mask tokens >= len in straddling tiles
        #pragma unroll
        for (int kt = 0; kt < 32; ++kt) {
            if (kt < ntk && kt * 16 + 15 >= len) {
                #pragma unroll
                for (int j = 0; j < 4; ++j) {
                    int tok = kt * 16 + g * 4 + j;
                    sacc[kt][j] = (tok < len) ? sacc[kt][j] : -1e30f;
                }
            }
        }
        // row max (per q = lane&15): in-lane + xor16/32
        float m = -1.0f;                          // pad-key shifted score
        #pragma unroll
        for (int kt = 0; kt < 32; ++kt)
            if (kt < ntk)
                m = fmaxf(m, fmaxf(fmaxf(sacc[kt][0], sacc[kt][1]),
                                   fmaxf(sacc[kt][2], sacc[kt][3])));
        m = fmaxf(m, __shfl_xor(m, 16, 64));
        m = fmaxf(m, __shfl_xor(m, 32, 64));

        float l = 0.f;
        f32x4 oacc = {0.f, 0.f, 0.f, 0.f};
        #pragma unroll
        for (int kts = 0; kts < 16; ++kts) {
            if (kts < nsup) {
                f32x4 s0 = sacc[2 * kts], s1 = sacc[2 * kts + 1];
                float p00 = __expf(s0[0] - m), p01 = __expf(s0[1] - m);
                float p02 = __expf(s0[2] - m), p03 = __expf(s0[3] - m);
                float p10 = __expf(s1[0] - m), p11 = __expf(s1[1] - m);
                float p12 = __expf(s1[2] - m), p13 = __expf(s1[3] - m);
                l += ((p00 + p01) + (p02 + p03)) + ((p10 + p11) + (p12 + p13));
                unsigned u0 = cvtpk(p00, p01), u1 = cvtpk(p02, p03);
                unsigned u2 = cvtpk(p10, p11), u3 = cvtpk(p12, p13);
                *(uint2*)&pw[q15 * 16 + 2 * g]     = make_uint2(u0, u1);
                *(uint2*)&pw[q15 * 16 + 8 + 2 * g] = make_uint2(u2, u3);
                uint4 bfr = *(uint4*)&pw[q15 * 16 + 4 * g];
                uint4 vfu = Vf[((long)bh * 16 + kts) * 64 + lane];
                oacc = __builtin_amdgcn_mfma_f32_16x16x32_bf16(
                    __builtin_bit_cast(short8, vfu),
                    __builtin_bit_cast(short8, bfr), oacc, 0, 0, 0);
            }
        }
        l += __shfl_xor(l, 16, 64);
        l += __shfl_xor(l, 32, 64);
        float tl = l + (float)(SS - len) * __expf(-1.0f - m);
        int q = qt * 16 + q15;
        float inv = (q < len) ? 1.0f / tl : 0.0f;
        #pragma unroll
        for (int j = 0; j < 4; ++j) osum[j] += oacc[j] * inv;
    }

    // sum over q (lane&15 groups)
    #pragma unroll
    for (int j = 0; j < 4; ++j) {
        float v = osum[j];
        v += __shfl_xor(v, 1, 64);
        v += __shfl_xor(v, 2, 64);
        v += __shfl_xor(v, 4, 64);
        v += __shfl_xor(v, 8, 64);
        osum[j] = v;
    }
    if (q15 == 0) {
        #pragma unroll
        for (int j = 0; j < 4; ++j) red[w][g * 4 + j] = osum[j];
    }
    __syncthreads();
    if (t < HD)
        tpart[blk * HD + t] = red[0][t] + red[1][t] + red[2][t] + red[3][t];
}

// ---------------------------------------------------------------------------
// K4: tsum = tpart halves + closed-form invalid-q term, then out-proj.
// out[b,d] = sum_c tsum[b,c]*Wout[d,c] + S*bout[d]
// ---------------------------------------------------------------------------
__global__ __launch_bounds__(DD) void k_out(const float* __restrict__ tpart,
                                            const float* __restrict__ Vsum,
                                            const int* __restrict__ lengths,
                                            const float* __restrict__ Wout,
                                            const float* __restrict__ bout,
                                            float* __restrict__ out) {
    int b = blockIdx.x;
    int d = threadIdx.x;
    int len = lengths[b];
    __shared__ float tr[DD];
    int bh = b * 8 + (d >> 4), dd = d & 15;
    float inv_q = (float)(SS - len) * (1.0f / (float)SS);
    tr[d] = tpart[(bh * 2 + 0) * HD + dd] + tpart[(bh * 2 + 1) * HD + dd]
          + inv_q * Vsum[bh * HD + dd];
    __syncthreads();
    float s = (float)SS * bout[d];
    #pragma unroll 8
    for (int c = 0; c < DD; ++c) s += tr[c] * Wout[d * DD + c];
    out[b * DD + d] = s;
}

extern "C" void kernel_launch(void* const* d_in, const int* in_sizes, int n_in,
                              void* d_out, int out_size, void* d_ws, size_t ws_size,
                              hipStream_t stream) {
    const float* feats = (const float*)d_in[0];
    const float* Win   = (const float*)d_in[1];
    const float* bin   = (const float*)d_in[2];
    const float* Wout  = (const float*)d_in[3];
    const float* bout  = (const float*)d_in[4];
    const int* bidx    = (const int*)d_in[7];
    const int* lengths = (const int*)d_in[8];
    float* out = (float*)d_out;

    char* ws = (char*)d_ws;
    // layout (bytes):
    //   xb   : [0, 4194304)          bf16 x, dead after k_qkv
    //   Vf   : [0, 4194304)          aliases xb (written by repack)
    //   Wb   : [4194304, 4292608)
    //   qkv  : [8388608, 33554432)   fp32
    //   Qf   : [33554432, 37748736)
    //   Kf   : [37748736, 41943040)
    //   Vsum : [41943040, 41959424)
    //   tpart: [41959424, 41992192)
    unsigned short* xb = (unsigned short*)ws;
    uint4* Vf          = (uint4*)ws;
    unsigned short* Wb = (unsigned short*)(ws + 4194304);
    float* qkv         = (float*)(ws + 8388608);
    uint4* Qf          = (uint4*)(ws + 33554432);
    uint4* Kf          = (uint4*)(ws + 37748736);
    float* Vsum        = (float*)(ws + 41943040);
    float* tpart       = (float*)(ws + 41959424);

    k_gather<<<BB * SS / 8, 256, 0, stream>>>(feats, bidx, xb);
    k_wconv<<<48, 256, 0, stream>>>(Win, Wb);
    k_qkv<<<128 * 3, 256, 0, stream>>>(xb, Wb, bin, qkv);
    k_repack<<<BB * NHH, 256, 0, stream>>>(qkv, Qf, Kf, Vf, Vsum);
    k_attn<<<BB * NHH * 2, 256, 0, stream>>>(Qf, Kf, Vf, lengths, tpart);
    k_out<<<BB, DD, 0, stream>>>(tpart, Vsum, lengths, Wout, bout, out);
}

// Round 8
// 217.553 us; speedup vs baseline: 2.3874x; 1.2361x over previous
//
#include <hip/hip_runtime.h>

#define NN 200000
#define DD 128
#define NHH 8
#define HD 16
#define BB 32
#define SS 512
#define QKV_LD 384

typedef __attribute__((ext_vector_type(8))) short short8;
typedef __attribute__((ext_vector_type(4))) float f32x4;

static __device__ __forceinline__ unsigned short f2bf(float f) {
    unsigned u = __float_as_uint(f);
    unsigned r = (u + 0x7FFFu + ((u >> 16) & 1u)) >> 16;   // RNE
    return (unsigned short)r;
}
static __device__ __forceinline__ unsigned pk2(float a, float b) {
    return (unsigned)f2bf(a) | ((unsigned)f2bf(b) << 16);
}
static __device__ __forceinline__ unsigned cvtpk(float a, float b) {
    unsigned r;
    asm("v_cvt_pk_bf16_f32 %0, %1, %2" : "=v"(r) : "v"(a), "v"(b));
    return r;
}

// ---------------------------------------------------------------------------
// K1: tree path-sum + gather -> bf16. Branchless 18 ancestor loads.
// ---------------------------------------------------------------------------
__global__ __launch_bounds__(256) void k_gather(const float* __restrict__ feats,
                                                const int* __restrict__ bidx,
                                                unsigned short* __restrict__ xb) {
    int t = threadIdx.x;
    int r = t >> 5, c4 = t & 31;
    long row = (long)blockIdx.x * 8 + r;
    int idx = bidx[row];
    int v = (idx >= 0 && idx < NN) ? idx : NN;
    const float4* f4 = (const float4*)feats;
    int a[18];
    #pragma unroll
    for (int k = 0; k < 18; ++k) {
        a[k] = v;
        v = (v == 0 || v >= NN) ? NN : (v - 1) >> 1;
    }
    float4 val[18];
    float fl[18];
    #pragma unroll
    for (int k = 0; k < 18; ++k) {
        int aa = a[k] < NN ? a[k] : 0;
        fl[k] = a[k] < NN ? 1.f : 0.f;
        val[k] = f4[(long)aa * 32 + c4];
    }
    float4 acc = make_float4(0.f, 0.f, 0.f, 0.f);
    #pragma unroll
    for (int k = 0; k < 18; ++k) {
        acc.x += fl[k] * val[k].x; acc.y += fl[k] * val[k].y;
        acc.z += fl[k] * val[k].z; acc.w += fl[k] * val[k].w;
    }
    ushort4 o;
    o.x = f2bf(acc.x); o.y = f2bf(acc.y); o.z = f2bf(acc.z); o.w = f2bf(acc.w);
    ((ushort4*)xb)[row * 32 + c4] = o;
}

// ---------------------------------------------------------------------------
// K2: qkv = x @ Win^T + bin via bf16 MFMA. B-tile staged directly from fp32
// Win with inline bf16 conversion (k_wconv fused away).
// ---------------------------------------------------------------------------
__global__ __launch_bounds__(256) void k_qkv(const unsigned short* __restrict__ xb,
                                             const float* __restrict__ Win,
                                             const float* __restrict__ bin,
                                             float* __restrict__ qkv) {
    __shared__ uint4 As4[128 * 16];
    __shared__ uint4 Bs4[128 * 16];
    int t = threadIdx.x;
    int rb = blockIdx.x / 3, cb = blockIdx.x % 3;
    long row0 = (long)rb * 128;
    int col0 = cb * 128;
    const uint4* ag = (const uint4*)xb + row0 * 16;
    #pragma unroll
    for (int n = 0; n < 8; ++n) {
        int idx = n * 256 + t;
        int r = idx >> 4, c = idx & 15;
        As4[r * 16 + (c ^ (r & 15))] = ag[idx];
        const float* wp = Win + (long)(col0 + r) * DD + c * 8;
        float4 f0 = *(const float4*)wp;
        float4 f1 = *(const float4*)(wp + 4);
        uint4 u;
        u.x = pk2(f0.x, f0.y); u.y = pk2(f0.z, f0.w);
        u.z = pk2(f1.x, f1.y); u.w = pk2(f1.z, f1.w);
        Bs4[r * 16 + (c ^ (r & 15))] = u;
    }
    __syncthreads();

    int lane = t & 63, w = t >> 6;
    int wr = (w >> 1) * 64, wc = (w & 1) * 64;
    int frow = lane & 15, fk = lane >> 4;
    f32x4 acc[4][4] = {};
    const short8* A8 = (const short8*)As4;
    const short8* B8 = (const short8*)Bs4;
    #pragma unroll
    for (int ks = 0; ks < 4; ++ks) {
        int chunk = ks * 4 + fk;
        short8 af[4], bf[4];
        #pragma unroll
        for (int mi = 0; mi < 4; ++mi) {
            int r = wr + mi * 16 + frow;
            af[mi] = A8[r * 16 + (chunk ^ (r & 15))];
        }
        #pragma unroll
        for (int ni = 0; ni < 4; ++ni) {
            int r = wc + ni * 16 + frow;
            bf[ni] = B8[r * 16 + (chunk ^ (r & 15))];
        }
        #pragma unroll
        for (int mi = 0; mi < 4; ++mi)
            #pragma unroll
            for (int ni = 0; ni < 4; ++ni)
                acc[mi][ni] = __builtin_amdgcn_mfma_f32_16x16x32_bf16(
                    af[mi], bf[ni], acc[mi][ni], 0, 0, 0);
    }

    int rg = lane >> 4;
    #pragma unroll
    for (int ni = 0; ni < 4; ++ni) {
        int col = col0 + wc + ni * 16 + frow;
        float bb = bin[col];
        #pragma unroll
        for (int mi = 0; mi < 4; ++mi) {
            #pragma unroll
            for (int j = 0; j < 4; ++j) {
                long r = row0 + wr + mi * 16 + rg * 4 + j;
                qkv[r * QKV_LD + col] = acc[mi][ni][j] + bb;
            }
        }
    }
}

// ---------------------------------------------------------------------------
// K2b: repack qkv fp32 -> MFMA frag layouts (bf16) + Vsum.
// Qf: tile qt, lane(r16,g2): token = qt*16+r16 (natural), d = 8*g2..+7.
//     Q pre-scaled 0.25.
// Kf: tile kt, lane(r16,g2): token = (kt>>1)*32 + (r16>>2)*8 + (kt&1)*4
//     + (r16&3)  -- PERMUTED so S^T C-regs land directly in PV B-frag order.
// Vf: super kts, lane(d=lane&15, gg): toks kts*32+gg*8..+7 (V^T A-frags).
// Vsum[bh][d] = sum over all tokens of V (pad rows exactly 0).
// ---------------------------------------------------------------------------
__global__ __launch_bounds__(256) void k_repack(const float* __restrict__ qkv,
                                                uint4* __restrict__ Qf,
                                                uint4* __restrict__ Kf,
                                                uint4* __restrict__ Vf,
                                                float* __restrict__ Vsum) {
    int bh = blockIdx.x, b = bh >> 3, h = bh & 7;
    int t = threadIdx.x;
    const float* base = qkv + (long)b * SS * QKV_LD;

    int l32 = t & 31, sub = t >> 5;
    int r16 = l32 & 15, g2 = l32 >> 4;
    #pragma unroll
    for (int pass = 0; pass < 4; ++pass) {
        int qt = pass * 8 + sub;
        // Q natural
        const float* qp = base + (long)(qt * 16 + r16) * QKV_LD + h * HD + 8 * g2;
        float4 f0 = *(const float4*)qp;
        float4 f1 = *(const float4*)(qp + 4);
        uint4 uq;
        uq.x = pk2(f0.x * 0.25f, f0.y * 0.25f);
        uq.y = pk2(f0.z * 0.25f, f0.w * 0.25f);
        uq.z = pk2(f1.x * 0.25f, f1.y * 0.25f);
        uq.w = pk2(f1.z * 0.25f, f1.w * 0.25f);
        Qf[((long)bh * 32 + qt) * 32 + l32] = uq;
        // K permuted
        int ktok = ((qt >> 1) << 5) + ((r16 >> 2) << 3) + ((qt & 1) << 2) + (r16 & 3);
        const float* kp = base + (long)ktok * QKV_LD + DD + h * HD + 8 * g2;
        float4 k0 = *(const float4*)kp;
        float4 k1 = *(const float4*)(kp + 4);
        uint4 uk;
        uk.x = pk2(k0.x, k0.y); uk.y = pk2(k0.z, k0.w);
        uk.z = pk2(k1.x, k1.y); uk.w = pk2(k1.z, k1.w);
        Kf[((long)bh * 32 + qt) * 32 + l32] = uk;
    }

    int lane = t & 63, vsub = t >> 6;
    int d = lane & 15, gg = lane >> 4;
    float vpart = 0.f;
    #pragma unroll
    for (int pass = 0; pass < 4; ++pass) {
        int kts = pass * 4 + vsub;
        int k0 = kts * 32 + gg * 8;
        float vv[8];
        #pragma unroll
        for (int i = 0; i < 8; ++i)
            vv[i] = base[(long)(k0 + i) * QKV_LD + 2 * DD + h * HD + d];
        #pragma unroll
        for (int i = 0; i < 8; ++i) vpart += vv[i];
        uint4 uv;
        uv.x = pk2(vv[0], vv[1]); uv.y = pk2(vv[2], vv[3]);
        uv.z = pk2(vv[4], vv[5]); uv.w = pk2(vv[6], vv[7]);
        Vf[((long)bh * 16 + kts) * 64 + lane] = uv;
    }
    __shared__ float vred[256];
    vred[t] = vpart;
    __syncthreads();
    if (t < HD) {
        float s = 0.f;
        #pragma unroll
        for (int j = 0; j < 16; ++j) s += vred[t + j * 16];
        Vsum[bh * HD + t] = s;
    }
}

// ---------------------------------------------------------------------------
// K3: MFMA flash attention, two-pass softmax, ZERO cross-lane P movement.
// Block = (bh, quarter qq), 4 waves, each wave 2 q-tiles qt = qq+4w+16i
// (interleaved for load balance). Pass 1: S^T = K Q^T, track max only
// (pad-K rows are exact zeros -> unmasked max is exact-math safe).
// Pass 2: recompute S^T per 32-tok super; thanks to the permuted Kf rows,
// lane(q,g)'s 8 scores are exactly PV B-frag toks 8g..8g+7: pack with
// cvt_pk and feed MFMA directly. O^T = V^T P^T. Shifted mask (valid=dot/4,
// pad=-1) with closed-form pad-key tail; invalid queries in k_out.
// ---------------------------------------------------------------------------
__global__ __launch_bounds__(256) void k_attn(const uint4* __restrict__ Qf,
                                              const uint4* __restrict__ Kf,
                                              const uint4* __restrict__ Vf,
                                              const int* __restrict__ lengths,
                                              float* __restrict__ tpart) {
    int blk = blockIdx.x;
    int bh = blk >> 2, qq = blk & 3;
    int b = bh >> 3;
    int t = threadIdx.x, lane = t & 63, w = t >> 6;
    int len = lengths[b];
    int q15 = lane & 15, g = lane >> 4;
    int nsup = (len + 31) >> 5;
    int ntk = nsup * 2;

    const uint4* Qb = Qf + (long)bh * 32 * 32;
    const uint4* Kb = Kf + (long)bh * 32 * 32;
    const uint4* Vb = Vf + (long)bh * 16 * 64;
    __shared__ float red[4][HD];
    const uint4 z4 = make_uint4(0u, 0u, 0u, 0u);
    const f32x4 cz = {0.f, 0.f, 0.f, 0.f};

    float osum[4] = {0.f, 0.f, 0.f, 0.f};

    #pragma unroll
    for (int i = 0; i < 2; ++i) {
        int qt = qq + 4 * w + 16 * i;
        if (qt * 16 >= len) continue;            // wave-uniform skip

        uint4 qfu = (lane < 32) ? Qb[qt * 32 + lane] : z4;
        short8 qf = __builtin_bit_cast(short8, qfu);

        // ---- pass 1: row max ----
        float m = -1.0f;                          // pad-key shifted score
        for (int kt = 0; kt < ntk; kt += 4) {
            #pragma unroll
            for (int u = 0; u < 4; ++u) {
                int k2 = (kt + u < ntk) ? kt + u : ntk - 1;
                uint4 kfu = (lane < 32) ? Kb[k2 * 32 + lane] : z4;
                f32x4 s = __builtin_amdgcn_mfma_f32_16x16x32_bf16(
                    __builtin_bit_cast(short8, kfu), qf, cz, 0, 0, 0);
                m = fmaxf(m, fmaxf(fmaxf(s[0], s[1]), fmaxf(s[2], s[3])));
            }
        }
        m = fmaxf(m, __shfl_xor(m, 16, 64));
        m = fmaxf(m, __shfl_xor(m, 32, 64));

        // ---- pass 2: exp + PV ----
        float l = 0.f;
        f32x4 oacc = {0.f, 0.f, 0.f, 0.f};
        bool strad = (len & 31) != 0;
        for (int kts = 0; kts < nsup; ++kts) {
            uint4 k0u = (lane < 32) ? Kb[(2 * kts) * 32 + lane] : z4;
            uint4 k1u = (lane < 32) ? Kb[(2 * kts + 1) * 32 + lane] : z4;
            f32x4 s0 = __builtin_amdgcn_mfma_f32_16x16x32_bf16(
                __builtin_bit_cast(short8, k0u), qf, cz, 0, 0, 0);
            f32x4 s1 = __builtin_amdgcn_mfma_f32_16x16x32_bf16(
                __builtin_bit_cast(short8, k1u), qf, cz, 0, 0, 0);
            if (kts == nsup - 1 && strad) {       // mask straddling pads
                int tb = kts * 32 + 8 * g;
                #pragma unroll
                for (int j = 0; j < 4; ++j) {
                    s0[j] = (tb + j < len) ? s0[j] : -1e30f;
                    s1[j] = (tb + 4 + j < len) ? s1[j] : -1e30f;
                }
            }
            float p0 = __expf(s0[0] - m), p1 = __expf(s0[1] - m);
            float p2 = __expf(s0[2] - m), p3 = __expf(s0[3] - m);
            float p4 = __expf(s1[0] - m), p5 = __expf(s1[1] - m);
            float p6 = __expf(s1[2] - m), p7 = __expf(s1[3] - m);
            l += ((p0 + p1) + (p2 + p3)) + ((p4 + p5) + (p6 + p7));
            uint4 pf;
            pf.x = cvtpk(p0, p1); pf.y = cvtpk(p2, p3);
            pf.z = cvtpk(p4, p5); pf.w = cvtpk(p6, p7);
            uint4 vfu = Vb[kts * 64 + lane];
            oacc = __builtin_amdgcn_mfma_f32_16x16x32_bf16(
                __builtin_bit_cast(short8, vfu),
                __builtin_bit_cast(short8, pf), oacc, 0, 0, 0);
        }
        l += __shfl_xor(l, 16, 64);
        l += __shfl_xor(l, 32, 64);
        float tl = l + (float)(SS - len) * __expf(-1.0f - m);
        float inv = (qt * 16 + q15 < len) ? 1.0f / tl : 0.0f;
        #pragma unroll
        for (int j = 0; j < 4; ++j) osum[j] += oacc[j] * inv;
    }

    #pragma unroll
    for (int j = 0; j < 4; ++j) {
        float v = osum[j];
        v += __shfl_xor(v, 1, 64);
        v += __shfl_xor(v, 2, 64);
        v += __shfl_xor(v, 4, 64);
        v += __shfl_xor(v, 8, 64);
        osum[j] = v;
    }
    if (q15 == 0) {
        #pragma unroll
        for (int j = 0; j < 4; ++j) red[w][g * 4 + j] = osum[j];
    }
    __syncthreads();
    if (t < HD)
        tpart[blk * HD + t] = red[0][t] + red[1][t] + red[2][t] + red[3][t];
}

// ---------------------------------------------------------------------------
// K4: tsum = 4 quarter-partials + closed-form invalid-q term, then out-proj.
// ---------------------------------------------------------------------------
__global__ __launch_bounds__(DD) void k_out(const float* __restrict__ tpart,
                                            const float* __restrict__ Vsum,
                                            const int* __restrict__ lengths,
                                            const float* __restrict__ Wout,
                                            const float* __restrict__ bout,
                                            float* __restrict__ out) {
    int b = blockIdx.x;
    int d = threadIdx.x;
    int len = lengths[b];
    __shared__ float tr[DD];
    int bh = b * 8 + (d >> 4), dd = d & 15;
    float inv_q = (float)(SS - len) * (1.0f / (float)SS);
    float s4 = tpart[(bh * 4 + 0) * HD + dd] + tpart[(bh * 4 + 1) * HD + dd]
             + tpart[(bh * 4 + 2) * HD + dd] + tpart[(bh * 4 + 3) * HD + dd];
    tr[d] = s4 + inv_q * Vsum[bh * HD + dd];
    __syncthreads();
    float s = (float)SS * bout[d];
    #pragma unroll 8
    for (int c = 0; c < DD; ++c) s += tr[c] * Wout[d * DD + c];
    out[b * DD + d] = s;
}

extern "C" void kernel_launch(void* const* d_in, const int* in_sizes, int n_in,
                              void* d_out, int out_size, void* d_ws, size_t ws_size,
                              hipStream_t stream) {
    const float* feats = (const float*)d_in[0];
    const float* Win   = (const float*)d_in[1];
    const float* bin   = (const float*)d_in[2];
    const float* Wout  = (const float*)d_in[3];
    const float* bout  = (const float*)d_in[4];
    const int* bidx    = (const int*)d_in[7];
    const int* lengths = (const int*)d_in[8];
    float* out = (float*)d_out;

    char* ws = (char*)d_ws;
    // layout (bytes):
    //   xb   : [0, 4194304)            bf16 x, dead after k_qkv
    //   Vf   : [0, 4194304)            aliases xb (written by repack)
    //   Vsum : [4194304, 4210688)
    //   tpart: [4259840, 4325376)      1024 x 16 fp32
    //   qkv  : [8388608, 33554432)     fp32
    //   Qf   : [33554432, 37748736)
    //   Kf   : [37748736, 41943040)
    unsigned short* xb = (unsigned short*)ws;
    uint4* Vf          = (uint4*)ws;
    float* Vsum        = (float*)(ws + 4194304);
    float* tpart       = (float*)(ws + 4259840);
    float* qkv         = (float*)(ws + 8388608);
    uint4* Qf          = (uint4*)(ws + 33554432);
    uint4* Kf          = (uint4*)(ws + 37748736);

    k_gather<<<BB * SS / 8, 256, 0, stream>>>(feats, bidx, xb);
    k_qkv<<<128 * 3, 256, 0, stream>>>(xb, Win, bin, qkv);
    k_repack<<<BB * NHH, 256, 0, stream>>>(qkv, Qf, Kf, Vf, Vsum);
    k_attn<<<BB * NHH * 4, 256, 0, stream>>>(Qf, Kf, Vf, lengths, tpart);
    k_out<<<BB, DD, 0, stream>>>(tpart, Vsum, lengths, Wout, bout, out);
}